// Round 5
// baseline (317.380 us; speedup 1.0000x reference)
//
#include <hip/hip_runtime.h>
#include <hip/hip_bf16.h>
#include <stdint.h>

typedef __hip_bfloat16 bf16;
typedef __attribute__((ext_vector_type(8))) short bf16x8;   // 8 bf16 = 4 VGPRs (MFMA A/B frag)
typedef __attribute__((ext_vector_type(4))) float f32x4;    // 16x16 MFMA C/D frag
typedef __attribute__((ext_vector_type(16))) float f32x16;  // 32x32 MFMA C/D frag
typedef __attribute__((ext_vector_type(4))) unsigned u32x4;

#define B_  2
#define L_  2048
#define D_  1024
#define H_  16
#define HD_ 64
#define BH_ 32
#define L2E 1.4426950408889634f

#define DEV static __device__ __forceinline__

DEV short f2bf(float f) {
    bf16 h = __float2bfloat16(f);
    return __builtin_bit_cast(short, h);
}

DEV unsigned pk2(float lo, float hi) {   // bf16(lo) | bf16(hi)<<16
    unsigned a = (unsigned short)__builtin_bit_cast(unsigned short, __float2bfloat16(lo));
    unsigned b = (unsigned short)__builtin_bit_cast(unsigned short, __float2bfloat16(hi));
    return a | (b << 16);
}

DEV f32x4 mfma16(bf16x8 a, bf16x8 b, f32x4 c) {
    return __builtin_amdgcn_mfma_f32_16x16x32_bf16(a, b, c, 0, 0, 0);
}
DEV f32x16 mfma32(bf16x8 a, bf16x8 b, f32x16 c) {
    return __builtin_amdgcn_mfma_f32_32x32x16_bf16(a, b, c, 0, 0, 0);
}

// async global->LDS, 16B per lane; lds ptr must be wave-uniform (HW adds lane*16)
DEV void async_ld16(const void* g, void* lds_uniform) {
    __builtin_amdgcn_global_load_lds((const __attribute__((address_space(1))) void*)g,
                                     (__attribute__((address_space(3))) void*)lds_uniform,
                                     16, 0, 0);
}

// XOR-swizzled element offset inside a [rows][64] bf16 tile (128B rows).
DEV int swz(int row, int col) {
    int blk = (row << 3) + (col >> 3);
    blk ^= (row & 7);
    return (blk << 3) + (col & 7);
}

// ---------------------------------------------------------------- cast x -> bf16
__global__ __launch_bounds__(256) void k_cast_x(const float* __restrict__ x,
                                                bf16* __restrict__ xb, int n8) {
    int i = blockIdx.x * 256 + threadIdx.x;
    if (i >= n8) return;
    const float4* src = (const float4*)x + (size_t)i * 2;
    float4 a = src[0], b = src[1];
    bf16x8 v;
    v[0]=f2bf(a.x); v[1]=f2bf(a.y); v[2]=f2bf(a.z); v[3]=f2bf(a.w);
    v[4]=f2bf(b.x); v[5]=f2bf(b.y); v[6]=f2bf(b.z); v[7]=f2bf(b.w);
    *(bf16x8*)(xb + (size_t)i * 8) = v;
}

// ------------------------------------------- cast + transpose weights -> WT[n][k] bf16
__global__ __launch_bounds__(256) void k_cast_wT(const float* __restrict__ W0, const float* __restrict__ W1,
                                                 const float* __restrict__ W2, const float* __restrict__ W3,
                                                 bf16* __restrict__ WT) {
    const float* W = (blockIdx.z == 0) ? W0 : (blockIdx.z == 1) ? W1 : (blockIdx.z == 2) ? W2 : W3;
    __shared__ float tile[64][65];
    const int r0 = blockIdx.y * 64, c0 = blockIdx.x * 64;
    const int tx = threadIdx.x & 63, ty = threadIdx.x >> 6;
    #pragma unroll
    for (int i = 0; i < 16; ++i) {
        int r = ty + i * 4;
        tile[r][tx] = W[(size_t)(r0 + r) * D_ + c0 + tx];
    }
    __syncthreads();
    bf16* out = WT + (size_t)blockIdx.z * D_ * D_;
    #pragma unroll
    for (int i = 0; i < 16; ++i) {
        int n = ty + i * 4;
        out[(size_t)(c0 + n) * D_ + r0 + tx] = __float2bfloat16(tile[tx][n]);
    }
}

// ---------------------------------------------------------------- GEMM 128x128, BK=64
template <int MODE>
__global__ __launch_bounds__(256) void k_gemm(const bf16* __restrict__ A, const bf16* __restrict__ BT,
                                              void* __restrict__ C) {
    __shared__ __align__(16) bf16 As[128 * 64];
    __shared__ __align__(16) bf16 Bs[128 * 64];
    const int t = threadIdx.x;
    const int w = t >> 6, lane = t & 63;
    const int lr = lane & 15, lg = lane >> 4;
    const int wr = (w >> 1) * 64, wc = (w & 1) * 64;
    const size_t am0 = (size_t)blockIdx.y * 128;
    const size_t bn0 = (size_t)blockIdx.x * 128;

    f32x4 acc[4][4] = {};

    for (int kt = 0; kt < 1024 / 64; ++kt) {
        const int k0 = kt * 64;
        if (kt) __syncthreads();
        #pragma unroll
        for (int c = 0; c < 4; ++c) {
            int phys = c * 256 + t;
            int lb = phys ^ ((phys >> 3) & 7);
            int row = lb >> 3, cb = lb & 7;
            int ldsoff = (c * 256 + w * 64) * 8;
            async_ld16(A  + (am0 + row) * 1024 + k0 + cb * 8, (void*)(As + ldsoff));
            async_ld16(BT + (bn0 + row) * 1024 + k0 + cb * 8, (void*)(Bs + ldsoff));
        }
        __syncthreads();
        bf16x8 af[4][2], bfv[4][2];
        #pragma unroll
        for (int mi = 0; mi < 4; ++mi)
            #pragma unroll
            for (int ks = 0; ks < 2; ++ks)
                af[mi][ks] = *(const bf16x8*)(As + swz(wr + mi * 16 + lr, ks * 32 + lg * 8));
        #pragma unroll
        for (int ni = 0; ni < 4; ++ni)
            #pragma unroll
            for (int ks = 0; ks < 2; ++ks)
                bfv[ni][ks] = *(const bf16x8*)(Bs + swz(wc + ni * 16 + lr, ks * 32 + lg * 8));
        #pragma unroll
        for (int mi = 0; mi < 4; ++mi)
            #pragma unroll
            for (int ni = 0; ni < 4; ++ni) {
                acc[mi][ni] = mfma16(af[mi][0], bfv[ni][0], acc[mi][ni]);
                acc[mi][ni] = mfma16(af[mi][1], bfv[ni][1], acc[mi][ni]);
            }
    }

    #pragma unroll
    for (int mi = 0; mi < 4; ++mi)
        #pragma unroll
        for (int ni = 0; ni < 4; ++ni)
            #pragma unroll
            for (int j = 0; j < 4; ++j) {
                size_t gm = am0 + wr + mi * 16 + lg * 4 + j;
                size_t gn = bn0 + wc + ni * 16 + lr;
                float v = acc[mi][ni][j];
                if (MODE == 0) {
                    int which = (int)(gn >> 10);
                    int h = (int)((gn >> 6) & 15);
                    int d = (int)(gn & 63);
                    int bb = (int)(gm >> 11);
                    int l = (int)(gm & 2047);
                    // fold 0.125 * log2(e) into Q so attention works in exp2 domain
                    if (which == 0) v *= 0.18033688011112042f;
                    bf16* dst = (bf16*)C + (size_t)which * ((size_t)BH_ * L_ * HD_);
                    dst[((size_t)(bb * H_ + h) * L_ + l) * HD_ + d] = __float2bfloat16(v);
                } else {
                    ((float*)C)[gm * 1024 + gn] = v;
                }
            }
}

// ---------------------------------------------------------------- V transpose per head
__global__ __launch_bounds__(256) void k_transpose_v(const bf16* __restrict__ Vb, bf16* __restrict__ VTb) {
    __shared__ __align__(16) short tile[64][80];
    const int bh = blockIdx.y;
    const int l0 = blockIdx.x * 64;
    const int t = threadIdx.x;
    const int rr = t >> 2, cc = (t & 3) * 16;
    const short* src = (const short*)(Vb + ((size_t)bh * L_ + l0 + rr) * HD_ + cc);
    *(bf16x8*)&tile[rr][cc]     = *(const bf16x8*)src;
    *(bf16x8*)&tile[rr][cc + 8] = *(const bf16x8*)(src + 8);
    __syncthreads();
    bf16x8 v0, v1;
    #pragma unroll
    for (int i = 0; i < 8; ++i) v0[i] = tile[cc + i][rr];
    #pragma unroll
    for (int i = 0; i < 8; ++i) v1[i] = tile[cc + 8 + i][rr];
    short* dst = (short*)(VTb + ((size_t)bh * HD_ + rr) * L_ + l0 + cc);
    *(bf16x8*)dst       = v0;
    *(bf16x8*)(dst + 8) = v1;
}

// ---------------------------------------------------------------- fused attention
// grid 1024 (XCD-swizzled -> (qt, h)), 256 threads = 4 waves, kv-split-4 (512 kv/wave).
// Waves independent in the loop (no barriers). Per iter (32 kv, both batches):
//   [kv0 loads][wait vmcnt(0)][pec from LDS][batch0][kv1 loads][PE-DMA next][wait vmcnt(4)][batch1]
// PE staged via global_load_lds, double-buffered, bank-swizzled via pre-swizzled source.
// 4-wave pairwise merge epilogue in overlaid LDS.
__global__ __launch_bounds__(256, 3) void k_attn(const bf16* __restrict__ Qb, const bf16* __restrict__ Kb,
                                                 const bf16* __restrict__ VTb, const float* __restrict__ PE,
                                                 bf16* __restrict__ Ob) {
    __shared__ __align__(16) char shm[34816];   // PE: 4 waves x 2 bufs x 4KB; merge: 2 x 17408B overlay
    const int bid = blockIdx.x;
    const int sw  = (bid & 7) * 128 + (bid >> 3);   // XCD swizzle: 2 heads per XCD
    const int qt  = sw & 63, h = sw >> 6;
    const int q0  = qt * 32;
    const int t   = threadIdx.x;
    const int w   = t >> 6;         // kv-quarter owner
    const int l   = t & 63;
    const int lq  = l & 31;         // this lane's q-row (and row-read index)
    const int lh  = l >> 5;         // half selector within wave

    // pi(lq): involution swapping 4-blocks 1<->2 and 5<->6 (A-row m holds K[kv0+pi(m)])
    const int pb = (lq >> 2) & 3;
    const int prow = lq + (pb == 1 ? 4 : (pb == 2 ? -4 : 0));

    // Q B-fragments, hoisted
    bf16x8 Qf[2][4];
    #pragma unroll
    for (int bi = 0; bi < 2; ++bi)
        #pragma unroll
        for (int dm = 0; dm < 4; ++dm)
            Qf[bi][dm] = *(const bf16x8*)(Qb + ((size_t)(bi * H_ + h) * L_ + q0 + lq) * HD_ + dm * 16 + lh * 8);

    const bf16* kb[2] = { Kb  + (size_t)(0 * H_ + h) * L_ * HD_,
                          Kb  + (size_t)(1 * H_ + h) * L_ * HD_ };
    const bf16* vb[2] = { VTb + (size_t)(0 * H_ + h) * HD_ * L_,
                          VTb + (size_t)(1 * H_ + h) * HD_ * L_ };

    // ---- PE DMA staging constants ----
    // instr c stages rows c*8..c*8+7; lane covers row (lane>>3), swizzled 16B col (lane&7)^(lane>>3)
    char* pewb = shm + w * 8192;                       // this wave's PE region (2 x 4KB)
    const int prow8 = l >> 3;
    const int pcb   = (l & 7) ^ prow8;                 // pre-swizzled source col-block
    const float* pesrc = PE + ((size_t)h * L_ + q0 + prow8) * L_ + pcb * 4;
    // LDS read slots: pec[g] = PE[lq][4 floats at block pi_b(2g+lh)]
    int peslot[4];
    #pragma unroll
    for (int g = 0; g < 4; ++g) {
        int x = 2 * g + lh;
        int pib = (x == 1) ? 2 : (x == 2) ? 1 : (x == 5) ? 6 : (x == 6) ? 5 : x;
        peslot[g] = lq * 8 + (pib ^ (lq & 7));
    }

    f32x16 o[2][2] = {};                       // [bi][d0-half]  O^T accum
    float mrun[2] = { -3e38f, -3e38f };
    float lpart[2] = { 0.f, 0.f };

    const int kvbase = w * 512;

#define PEDMA(IT) {                                                                     \
    char* dst = pewb + ((IT) & 1) * 4096;                                               \
    const float* s0 = pesrc + (size_t)kvbase + ((IT) < 16 ? (IT) : 15) * 32;            \
    _Pragma("unroll") for (int c = 0; c < 4; ++c)                                       \
        async_ld16(s0 + (size_t)(c * 8) * L_, (void*)(dst + c * 1024));                 \
}

#define COMPUTE(BI, KF, VF) {                                                           \
    f32x16 s = {};                                                                      \
    _Pragma("unroll") for (int dm = 0; dm < 4; ++dm)                                    \
        s = mfma32(KF[dm], Qf[BI][dm], s);                                              \
    float v[16];                                                                        \
    _Pragma("unroll") for (int r = 0; r < 16; ++r)                                      \
        v[r] = fmaf(pec[r >> 2][r & 3], L2E, s[r]);                                     \
    float t0 = fmaxf(fmaxf(v[0], v[1]), fmaxf(v[2], v[3]));                             \
    float t1 = fmaxf(fmaxf(v[4], v[5]), fmaxf(v[6], v[7]));                             \
    float t2 = fmaxf(fmaxf(v[8], v[9]), fmaxf(v[10], v[11]));                           \
    float t3 = fmaxf(fmaxf(v[12], v[13]), fmaxf(v[14], v[15]));                         \
    float vmh = fmaxf(fmaxf(t0, t1), fmaxf(t2, t3));                                    \
    float vm = fmaxf(vmh, __shfl_xor(vmh, 32, 64));                                     \
    float mold = mrun[BI];                                                              \
    float mnew = mold;                                                                  \
    if (!__all(vm <= mold + 10.f)) {                                                    \
        mnew = fmaxf(mold, vm);                                                         \
        float scl = __builtin_amdgcn_exp2f(mold - mnew);                                \
        mrun[BI] = mnew;                                                                \
        lpart[BI] *= scl;                                                               \
        _Pragma("unroll") for (int r = 0; r < 16; ++r) { o[BI][0][r] *= scl; o[BI][1][r] *= scl; } \
    }                                                                                   \
    float p[16], ssum = 0.f;                                                            \
    _Pragma("unroll") for (int r = 0; r < 16; ++r) {                                    \
        p[r] = __builtin_amdgcn_exp2f(v[r] - mnew);                                     \
        ssum += p[r];                                                                   \
    }                                                                                   \
    lpart[BI] += ssum;                                                                  \
    unsigned a[8];                                                                      \
    _Pragma("unroll") for (int j = 0; j < 8; ++j)                                       \
        a[j] = pk2(p[2 * j], p[2 * j + 1]);                                             \
    u32x4 w0v = { a[0], a[1], a[2], a[3] };                                             \
    u32x4 w1v = { a[4], a[5], a[6], a[7] };                                             \
    bf16x8 pf0 = __builtin_bit_cast(bf16x8, w0v);                                       \
    bf16x8 pf1 = __builtin_bit_cast(bf16x8, w1v);                                       \
    o[BI][0] = mfma32(VF[0][0], pf0, o[BI][0]);                                         \
    o[BI][0] = mfma32(VF[0][1], pf1, o[BI][0]);                                         \
    o[BI][1] = mfma32(VF[1][0], pf0, o[BI][1]);                                         \
    o[BI][1] = mfma32(VF[1][1], pf1, o[BI][1]);                                         \
}

    // prologue: stage PE tile 0
    PEDMA(0)

    for (int it = 0; it < 16; ++it) {
        const int kv0 = kvbase + it * 32;
        // ---- batch0 K/V loads (VMEM issue first) ----
        bf16x8 kf0[4], vf0[2][2];
        #pragma unroll
        for (int dm = 0; dm < 4; ++dm)
            kf0[dm] = *(const bf16x8*)(kb[0] + (size_t)(kv0 + prow) * HD_ + dm * 16 + lh * 8);
        #pragma unroll
        for (int d0 = 0; d0 < 2; ++d0)
            #pragma unroll
            for (int m = 0; m < 2; ++m)
                vf0[d0][m] = *(const bf16x8*)(vb[0] + (size_t)(d0 * 32 + lq) * L_ + kv0 + m * 16 + lh * 8);
        asm volatile("" ::: "memory");
        asm volatile("s_waitcnt vmcnt(0)" ::: "memory");   // kv0 + PE(it) landed
        // PE tile from LDS
        const float4* pes = (const float4*)(pewb + (it & 1) * 4096);
        float4 pec[4];
        #pragma unroll
        for (int g = 0; g < 4; ++g) pec[g] = pes[peslot[g]];
        COMPUTE(0, kf0, vf0)
        // ---- batch1 loads, then PE DMA for next tile ----
        bf16x8 kf1[4], vf1[2][2];
        #pragma unroll
        for (int dm = 0; dm < 4; ++dm)
            kf1[dm] = *(const bf16x8*)(kb[1] + (size_t)(kv0 + prow) * HD_ + dm * 16 + lh * 8);
        #pragma unroll
        for (int d0 = 0; d0 < 2; ++d0)
            #pragma unroll
            for (int m = 0; m < 2; ++m)
                vf1[d0][m] = *(const bf16x8*)(vb[1] + (size_t)(d0 * 32 + lq) * L_ + kv0 + m * 16 + lh * 8);
        asm volatile("" ::: "memory");
        PEDMA(it + 1)
        asm volatile("" ::: "memory");
        asm volatile("s_waitcnt vmcnt(4)" ::: "memory");   // kv1 done, PE(it+1) still flying
        COMPUTE(1, kf1, vf1)
    }
#undef COMPUTE
#undef PEDMA

    // combine l across the two lane-halves (same q)
    float lsum[2];
    #pragma unroll
    for (int bi = 0; bi < 2; ++bi)
        lsum[bi] = lpart[bi] + __shfl_xor(lpart[bi], 32, 64);

    // drain dangling PE DMA before LDS reuse
    asm volatile("s_waitcnt vmcnt(0)" ::: "memory");
    __syncthreads();

    // ---- 4-wave pairwise merge: (0+=1, 2+=3) then (0+=2) ----
    float* mg = (float*)shm;   // two regions of 4352 floats
#define DUMP(REG) {                                                                     \
    float* d = mg + (REG) * 4352 + l * 68;                                              \
    _Pragma("unroll") for (int bi = 0; bi < 2; ++bi) {                                  \
        _Pragma("unroll") for (int d0 = 0; d0 < 2; ++d0)                                \
            _Pragma("unroll") for (int r = 0; r < 16; ++r)                              \
                d[bi * 32 + d0 * 16 + r] = o[bi][d0][r];                                \
        d[64 + bi] = mrun[bi]; d[66 + bi] = lsum[bi];                                   \
    }                                                                                   \
}
#define MERGE(REG) {                                                                    \
    const float* s = mg + (REG) * 4352 + l * 68;                                        \
    _Pragma("unroll") for (int bi = 0; bi < 2; ++bi) {                                  \
        float m1 = s[64 + bi], l1 = s[66 + bi];                                         \
        float ms = fmaxf(mrun[bi], m1);                                                 \
        float c0 = __builtin_amdgcn_exp2f(mrun[bi] - ms);                               \
        float c1 = __builtin_amdgcn_exp2f(m1 - ms);                                     \
        mrun[bi] = ms;                                                                  \
        lsum[bi] = lsum[bi] * c0 + l1 * c1;                                             \
        _Pragma("unroll") for (int d0 = 0; d0 < 2; ++d0)                                \
            _Pragma("unroll") for (int r = 0; r < 16; ++r)                              \
                o[bi][d0][r] = o[bi][d0][r] * c0 + s[bi * 32 + d0 * 16 + r] * c1;       \
    }                                                                                   \
}
    if (w == 1) DUMP(0)
    if (w == 3) DUMP(1)
    __syncthreads();
    if (w == 0) MERGE(0)
    if (w == 2) MERGE(1)
    __syncthreads();
    if (w == 2) DUMP(0)
    __syncthreads();
    if (w == 0) {
        MERGE(0)
        #pragma unroll
        for (int bi = 0; bi < 2; ++bi) {
            float inv = __builtin_amdgcn_rcpf(lsum[bi]);
            #pragma unroll
            for (int d0 = 0; d0 < 2; ++d0)
                #pragma unroll
                for (int r = 0; r < 16; r += 2) {
                    float e0 = o[bi][d0][r] * inv;
                    float e1 = o[bi][d0][r + 1] * inv;
                    int d = d0 * 32 + ((r & 3) + 8 * (r >> 2)) + lh * 4;
                    *(unsigned*)(Ob + ((size_t)bi * L_ + q0 + lq) * D_ + h * HD_ + d) = pk2(e0, e1);
                }
        }
    }
#undef DUMP
#undef MERGE
}

// ---------------------------------------------------------------- launch
extern "C" void kernel_launch(void* const* d_in, const int* in_sizes, int n_in,
                              void* d_out, int out_size, void* d_ws, size_t ws_size,
                              hipStream_t stream) {
    const float* x  = (const float*)d_in[0];
    const float* pe = (const float*)d_in[1];
    const float* Wq = (const float*)d_in[2];
    const float* Wk = (const float*)d_in[3];
    const float* Wv = (const float*)d_in[4];
    const float* Wo = (const float*)d_in[5];
    float* out = (float*)d_out;

    const size_t MD = (size_t)4096 * 1024;
    const size_t HS = (size_t)BH_ * L_ * HD_;

    bf16* Xb  = (bf16*)d_ws;        // x in bf16            [4096][1024]
    bf16* WT  = Xb + MD;            // WqT|WkT|WvT|WoT      [4096][1024]
    bf16* Qb  = WT + MD;            // [bh][L][64]  (pre-scaled by 0.125*log2e)
    bf16* Kb  = Qb + HS;
    bf16* Vb  = Kb + HS;
    bf16* VTb = Vb + HS;            // [bh][64][L]
    bf16* Ob  = VTb + HS;           // attention out        [4096][1024]

    k_cast_x<<<2048, 256, 0, stream>>>(x, Xb, 4096 * 1024 / 8);
    k_cast_wT<<<dim3(16, 16, 4), 256, 0, stream>>>(Wq, Wk, Wv, Wo, WT);
    k_gemm<0><<<dim3(24, 32), 256, 0, stream>>>(Xb, WT, (void*)Qb);          // QKV, N=3072
    k_transpose_v<<<dim3(32, 32), 256, 0, stream>>>(Vb, VTb);
    k_attn<<<1024, 256, 0, stream>>>(Qb, Kb, VTb, pe, Ob);
    k_gemm<1><<<dim3(8, 32), 256, 0, stream>>>(Ob, WT + (size_t)3072 * 1024, (void*)out); // out-proj
}

// Round 6
// 198.863 us; speedup vs baseline: 1.5960x; 1.5960x over previous
//
#include <hip/hip_runtime.h>
#include <hip/hip_bf16.h>
#include <stdint.h>

typedef __hip_bfloat16 bf16;
typedef __attribute__((ext_vector_type(8))) short bf16x8;   // 8 bf16 = 4 VGPRs (MFMA A/B frag)
typedef __attribute__((ext_vector_type(4))) float f32x4;    // 16x16 MFMA C/D frag
typedef __attribute__((ext_vector_type(16))) float f32x16;  // 32x32 MFMA C/D frag
typedef __attribute__((ext_vector_type(4))) unsigned u32x4;

#define B_  2
#define L_  2048
#define D_  1024
#define H_  16
#define HD_ 64
#define BH_ 32
#define L2E 1.4426950408889634f

#define DEV static __device__ __forceinline__

DEV short f2bf(float f) {
    bf16 h = __float2bfloat16(f);
    return __builtin_bit_cast(short, h);
}

DEV unsigned pk2(float lo, float hi) {   // bf16(lo) | bf16(hi)<<16
    unsigned a = (unsigned short)__builtin_bit_cast(unsigned short, __float2bfloat16(lo));
    unsigned b = (unsigned short)__builtin_bit_cast(unsigned short, __float2bfloat16(hi));
    return a | (b << 16);
}

DEV f32x4 mfma16(bf16x8 a, bf16x8 b, f32x4 c) {
    return __builtin_amdgcn_mfma_f32_16x16x32_bf16(a, b, c, 0, 0, 0);
}
DEV f32x16 mfma32(bf16x8 a, bf16x8 b, f32x16 c) {
    return __builtin_amdgcn_mfma_f32_32x32x16_bf16(a, b, c, 0, 0, 0);
}

// async global->LDS, 16B per lane; lds ptr must be wave-uniform (HW adds lane*16)
DEV void async_ld16(const void* g, void* lds_uniform) {
    __builtin_amdgcn_global_load_lds((const __attribute__((address_space(1))) void*)g,
                                     (__attribute__((address_space(3))) void*)lds_uniform,
                                     16, 0, 0);
}

// XOR-swizzled element offset inside a [rows][64] bf16 tile (128B rows).
DEV int swz(int row, int col) {
    int blk = (row << 3) + (col >> 3);
    blk ^= (row & 7);
    return (blk << 3) + (col & 7);
}

// ---------------------------------------------------------------- cast x -> bf16
__global__ __launch_bounds__(256) void k_cast_x(const float* __restrict__ x,
                                                bf16* __restrict__ xb, int n8) {
    int i = blockIdx.x * 256 + threadIdx.x;
    if (i >= n8) return;
    const float4* src = (const float4*)x + (size_t)i * 2;
    float4 a = src[0], b = src[1];
    bf16x8 v;
    v[0]=f2bf(a.x); v[1]=f2bf(a.y); v[2]=f2bf(a.z); v[3]=f2bf(a.w);
    v[4]=f2bf(b.x); v[5]=f2bf(b.y); v[6]=f2bf(b.z); v[7]=f2bf(b.w);
    *(bf16x8*)(xb + (size_t)i * 8) = v;
}

// ------------------------------------------- cast + transpose weights -> WT[n][k] bf16
__global__ __launch_bounds__(256) void k_cast_wT(const float* __restrict__ W0, const float* __restrict__ W1,
                                                 const float* __restrict__ W2, const float* __restrict__ W3,
                                                 bf16* __restrict__ WT) {
    const float* W = (blockIdx.z == 0) ? W0 : (blockIdx.z == 1) ? W1 : (blockIdx.z == 2) ? W2 : W3;
    __shared__ float tile[64][65];
    const int r0 = blockIdx.y * 64, c0 = blockIdx.x * 64;
    const int tx = threadIdx.x & 63, ty = threadIdx.x >> 6;
    #pragma unroll
    for (int i = 0; i < 16; ++i) {
        int r = ty + i * 4;
        tile[r][tx] = W[(size_t)(r0 + r) * D_ + c0 + tx];
    }
    __syncthreads();
    bf16* out = WT + (size_t)blockIdx.z * D_ * D_;
    #pragma unroll
    for (int i = 0; i < 16; ++i) {
        int n = ty + i * 4;
        out[(size_t)(c0 + n) * D_ + r0 + tx] = __float2bfloat16(tile[tx][n]);
    }
}

// ---------------------------------------------------------------- GEMM 128x128, BK=64
template <int MODE>
__global__ __launch_bounds__(256) void k_gemm(const bf16* __restrict__ A, const bf16* __restrict__ BT,
                                              void* __restrict__ C) {
    __shared__ __align__(16) bf16 As[128 * 64];
    __shared__ __align__(16) bf16 Bs[128 * 64];
    const int t = threadIdx.x;
    const int w = t >> 6, lane = t & 63;
    const int lr = lane & 15, lg = lane >> 4;
    const int wr = (w >> 1) * 64, wc = (w & 1) * 64;
    const size_t am0 = (size_t)blockIdx.y * 128;
    const size_t bn0 = (size_t)blockIdx.x * 128;

    f32x4 acc[4][4] = {};

    for (int kt = 0; kt < 1024 / 64; ++kt) {
        const int k0 = kt * 64;
        if (kt) __syncthreads();
        #pragma unroll
        for (int c = 0; c < 4; ++c) {
            int phys = c * 256 + t;
            int lb = phys ^ ((phys >> 3) & 7);
            int row = lb >> 3, cb = lb & 7;
            int ldsoff = (c * 256 + w * 64) * 8;
            async_ld16(A  + (am0 + row) * 1024 + k0 + cb * 8, (void*)(As + ldsoff));
            async_ld16(BT + (bn0 + row) * 1024 + k0 + cb * 8, (void*)(Bs + ldsoff));
        }
        __syncthreads();
        bf16x8 af[4][2], bfv[4][2];
        #pragma unroll
        for (int mi = 0; mi < 4; ++mi)
            #pragma unroll
            for (int ks = 0; ks < 2; ++ks)
                af[mi][ks] = *(const bf16x8*)(As + swz(wr + mi * 16 + lr, ks * 32 + lg * 8));
        #pragma unroll
        for (int ni = 0; ni < 4; ++ni)
            #pragma unroll
            for (int ks = 0; ks < 2; ++ks)
                bfv[ni][ks] = *(const bf16x8*)(Bs + swz(wc + ni * 16 + lr, ks * 32 + lg * 8));
        #pragma unroll
        for (int mi = 0; mi < 4; ++mi)
            #pragma unroll
            for (int ni = 0; ni < 4; ++ni) {
                acc[mi][ni] = mfma16(af[mi][0], bfv[ni][0], acc[mi][ni]);
                acc[mi][ni] = mfma16(af[mi][1], bfv[ni][1], acc[mi][ni]);
            }
    }

    #pragma unroll
    for (int mi = 0; mi < 4; ++mi)
        #pragma unroll
        for (int ni = 0; ni < 4; ++ni)
            #pragma unroll
            for (int j = 0; j < 4; ++j) {
                size_t gm = am0 + wr + mi * 16 + lg * 4 + j;
                size_t gn = bn0 + wc + ni * 16 + lr;
                float v = acc[mi][ni][j];
                if (MODE == 0) {
                    int which = (int)(gn >> 10);
                    int h = (int)((gn >> 6) & 15);
                    int d = (int)(gn & 63);
                    int bb = (int)(gm >> 11);
                    int l = (int)(gm & 2047);
                    // fold 0.125 * log2(e) into Q so attention works in exp2 domain
                    if (which == 0) v *= 0.18033688011112042f;
                    bf16* dst = (bf16*)C + (size_t)which * ((size_t)BH_ * L_ * HD_);
                    dst[((size_t)(bb * H_ + h) * L_ + l) * HD_ + d] = __float2bfloat16(v);
                } else {
                    ((float*)C)[gm * 1024 + gn] = v;
                }
            }
}

// ---------------------------------------------------------------- V transpose per head
__global__ __launch_bounds__(256) void k_transpose_v(const bf16* __restrict__ Vb, bf16* __restrict__ VTb) {
    __shared__ __align__(16) short tile[64][80];
    const int bh = blockIdx.y;
    const int l0 = blockIdx.x * 64;
    const int t = threadIdx.x;
    const int rr = t >> 2, cc = (t & 3) * 16;
    const short* src = (const short*)(Vb + ((size_t)bh * L_ + l0 + rr) * HD_ + cc);
    *(bf16x8*)&tile[rr][cc]     = *(const bf16x8*)src;
    *(bf16x8*)&tile[rr][cc + 8] = *(const bf16x8*)(src + 8);
    __syncthreads();
    bf16x8 v0, v1;
    #pragma unroll
    for (int i = 0; i < 8; ++i) v0[i] = tile[cc + i][rr];
    #pragma unroll
    for (int i = 0; i < 8; ++i) v1[i] = tile[cc + 8 + i][rr];
    short* dst = (short*)(VTb + ((size_t)bh * HD_ + rr) * L_ + l0 + cc);
    *(bf16x8*)dst       = v0;
    *(bf16x8*)(dst + 8) = v1;
}

// ---------------------------------------------------------------- fused attention
// grid 512 (XCD-swizzled -> 2 heads/XCD), 128 threads = 2 waves, each wave 32 q-rows,
// full 2048 kv, both batches. K/V: swizzled global_load_lds double-buffer (tile=64 kv),
// counted vmcnt(24) -- DMA+PE stay in flight across raw barriers. Softmax fully
// in-register (R4-verified pi-permuted 32x32 layout). PE: per-lane float4 from global,
// one body (~2 tiles) of prefetch depth.
__global__ __launch_bounds__(128, 1) void k_attn(const bf16* __restrict__ Qb, const bf16* __restrict__ Kb,
                                                 const bf16* __restrict__ VTb, const float* __restrict__ PE,
                                                 bf16* __restrict__ Ob) {
    __shared__ __align__(16) bf16 Kls[2][2][64 * 64];   // [buf][batch][64 kv][64 d]  (swizzled)
    __shared__ __align__(16) bf16 Vls[2][2][64 * 64];   // [buf][batch][64 d][64 kv]  (swizzled)

    const int bid = blockIdx.x;
    const int sw  = (bid & 7) * 64 + (bid >> 3);   // XCD swizzle: 2 heads per XCD
    const int qt  = sw & 31, h = sw >> 5;
    const int q0  = qt * 64;
    const int t   = threadIdx.x;
    const int w   = t >> 6;         // wave id (q sub-tile)
    const int l   = t & 63;
    const int lq  = l & 31;         // this lane's q-row
    const int lh  = l >> 5;         // half selector within wave

    // pi(lq): involution swapping 4-blocks 1<->2 and 5<->6 (A-row m holds K[pi(m)])
    const int pb = (lq >> 2) & 3;
    const int prow = lq + (pb == 1 ? 4 : (pb == 2 ? -4 : 0));

    // Q B-fragments, hoisted (Q pre-scaled by 0.125*log2e at projection)
    bf16x8 Qf[2][4];
    #pragma unroll
    for (int bi = 0; bi < 2; ++bi)
        #pragma unroll
        for (int dm = 0; dm < 4; ++dm)
            Qf[bi][dm] = *(const bf16x8*)(Qb + ((size_t)(bi * H_ + h) * L_ + q0 + w * 32 + lq) * HD_ + dm * 16 + lh * 8);

    const bf16* kb[2] = { Kb  + (size_t)(0 * H_ + h) * L_ * HD_,
                          Kb  + (size_t)(1 * H_ + h) * L_ * HD_ };
    const bf16* vb[2] = { VTb + (size_t)(0 * H_ + h) * HD_ * L_,
                          VTb + (size_t)(1 * H_ + h) * HD_ * L_ };
    const float* perow = PE + ((size_t)h * L_ + q0 + w * 32 + lq) * L_;

    // PE gather offsets within a 32-kv block (R4-verified pi mapping)
    int peoff[4];
    #pragma unroll
    for (int g = 0; g < 4; ++g)
        peoff[g] = (g >> 1) * 16 + (g & 1) * 4 + lh * 8;

    // staging constants: slot s = c*128+t; row = s>>3; src 16B-block = (s&7)^(row&7)
    int srow[4], sblk[4];
    #pragma unroll
    for (int c = 0; c < 4; ++c) {
        int s = c * 128 + t;
        srow[c] = s >> 3;
        sblk[c] = (s & 7) ^ (srow[c] & 7);
    }

    // LDS read offsets (swizzled): K row R=ks*32+prow, col-block dm*2+lh
    int kro[2][4];
    #pragma unroll
    for (int ks = 0; ks < 2; ++ks)
        #pragma unroll
        for (int dm = 0; dm < 4; ++dm) {
            int R = ks * 32 + prow, cb = dm * 2 + lh;
            kro[ks][dm] = R * 64 + ((cb ^ (R & 7)) * 8);
        }
    // V row R=d0*32+lq, col-block ks*4+m*2+lh
    int vro[2][2][2];
    #pragma unroll
    for (int ks = 0; ks < 2; ++ks)
        #pragma unroll
        for (int d0 = 0; d0 < 2; ++d0)
            #pragma unroll
            for (int m = 0; m < 2; ++m) {
                int R = d0 * 32 + lq, cb = ks * 4 + m * 2 + lh;
                vro[ks][d0][m] = R * 64 + ((cb ^ (R & 7)) * 8);
            }

    f32x16 o[2][2] = {};                       // [bi][d0-half]  O^T accum
    float mrun[2] = { -3e38f, -3e38f };
    float lpart[2] = { 0.f, 0.f };
    float4 peE[8], peO[8];

#define STAGE(BUF, TILE) {                                                              \
    _Pragma("unroll") for (int c = 0; c < 4; ++c) {                                     \
        async_ld16(kb[0] + (size_t)((TILE) * 64 + srow[c]) * HD_ + sblk[c] * 8,         \
                   (void*)(&Kls[BUF][0][0] + (c * 128 + w * 64) * 8));                  \
        async_ld16(kb[1] + (size_t)((TILE) * 64 + srow[c]) * HD_ + sblk[c] * 8,         \
                   (void*)(&Kls[BUF][1][0] + (c * 128 + w * 64) * 8));                  \
        async_ld16(vb[0] + (size_t)srow[c] * L_ + (TILE) * 64 + sblk[c] * 8,            \
                   (void*)(&Vls[BUF][0][0] + (c * 128 + w * 64) * 8));                  \
        async_ld16(vb[1] + (size_t)srow[c] * L_ + (TILE) * 64 + sblk[c] * 8,            \
                   (void*)(&Vls[BUF][1][0] + (c * 128 + w * 64) * 8));                  \
    }                                                                                   \
}

#define PELOAD(DST, TILE) {                                                             \
    _Pragma("unroll") for (int u = 0; u < 8; ++u)                                       \
        DST[u] = *(const float4*)(perow + (size_t)(TILE) * 64 + (u >> 2) * 32 + peoff[u & 3]); \
}

#define COMPUTE32(BI, KS, PEA, KL, VL) {                                                \
    bf16x8 kf0_ = *(const bf16x8*)((KL) + kro[KS][0]);                                  \
    bf16x8 kf1_ = *(const bf16x8*)((KL) + kro[KS][1]);                                  \
    bf16x8 kf2_ = *(const bf16x8*)((KL) + kro[KS][2]);                                  \
    bf16x8 kf3_ = *(const bf16x8*)((KL) + kro[KS][3]);                                  \
    f32x16 s = {};                                                                      \
    s = mfma32(kf0_, Qf[BI][0], s);                                                     \
    s = mfma32(kf1_, Qf[BI][1], s);                                                     \
    s = mfma32(kf2_, Qf[BI][2], s);                                                     \
    s = mfma32(kf3_, Qf[BI][3], s);                                                     \
    float v_[16];                                                                       \
    _Pragma("unroll") for (int r = 0; r < 16; ++r)                                      \
        v_[r] = fmaf(PEA[(KS) * 4 + (r >> 2)][r & 3], L2E, s[r]);                       \
    float t0_ = fmaxf(fmaxf(v_[0], v_[1]), fmaxf(v_[2], v_[3]));                        \
    float t1_ = fmaxf(fmaxf(v_[4], v_[5]), fmaxf(v_[6], v_[7]));                        \
    float t2_ = fmaxf(fmaxf(v_[8], v_[9]), fmaxf(v_[10], v_[11]));                      \
    float t3_ = fmaxf(fmaxf(v_[12], v_[13]), fmaxf(v_[14], v_[15]));                    \
    float vmh_ = fmaxf(fmaxf(t0_, t1_), fmaxf(t2_, t3_));                               \
    float vm_ = fmaxf(vmh_, __shfl_xor(vmh_, 32, 64));                                  \
    float mold_ = mrun[BI];                                                             \
    float mnew_ = mold_;                                                                \
    if (!__all(vm_ <= mold_ + 10.f)) {                                                  \
        mnew_ = fmaxf(mold_, vm_);                                                      \
        float scl_ = __builtin_amdgcn_exp2f(mold_ - mnew_);                             \
        mrun[BI] = mnew_;                                                               \
        lpart[BI] *= scl_;                                                              \
        _Pragma("unroll") for (int r = 0; r < 16; ++r) { o[BI][0][r] *= scl_; o[BI][1][r] *= scl_; } \
    }                                                                                   \
    float p_[16], ssum_ = 0.f;                                                          \
    _Pragma("unroll") for (int r = 0; r < 16; ++r) {                                    \
        p_[r] = __builtin_amdgcn_exp2f(v_[r] - mnew_);                                  \
        ssum_ += p_[r];                                                                 \
    }                                                                                   \
    lpart[BI] += ssum_;                                                                 \
    unsigned a_[8];                                                                     \
    _Pragma("unroll") for (int j = 0; j < 8; ++j)                                       \
        a_[j] = pk2(p_[2 * j], p_[2 * j + 1]);                                          \
    u32x4 w0v_ = { a_[0], a_[1], a_[2], a_[3] };                                        \
    u32x4 w1v_ = { a_[4], a_[5], a_[6], a_[7] };                                        \
    bf16x8 pf0_ = __builtin_bit_cast(bf16x8, w0v_);                                     \
    bf16x8 pf1_ = __builtin_bit_cast(bf16x8, w1v_);                                     \
    o[BI][0] = mfma32(*(const bf16x8*)((VL) + vro[KS][0][0]), pf0_, o[BI][0]);          \
    o[BI][0] = mfma32(*(const bf16x8*)((VL) + vro[KS][0][1]), pf1_, o[BI][0]);          \
    o[BI][1] = mfma32(*(const bf16x8*)((VL) + vro[KS][1][0]), pf0_, o[BI][1]);          \
    o[BI][1] = mfma32(*(const bf16x8*)((VL) + vro[KS][1][1]), pf1_, o[BI][1]);          \
}

#define HALF(BUF, PEA, TILE, PFT) {                                                     \
    COMPUTE32(0, 0, PEA, &Kls[BUF][0][0], &Vls[BUF][0][0])                              \
    COMPUTE32(0, 1, PEA, &Kls[BUF][0][0], &Vls[BUF][0][0])                              \
    COMPUTE32(1, 0, PEA, &Kls[BUF][1][0], &Vls[BUF][1][0])                              \
    COMPUTE32(1, 1, PEA, &Kls[BUF][1][0], &Vls[BUF][1][0])                              \
    PELOAD(PEA, PFT)                                                                    \
    __builtin_amdgcn_s_barrier();                                                       \
    STAGE(BUF, PFT)                                                                     \
    asm volatile("s_waitcnt vmcnt(24)" ::: "memory");                                   \
    __builtin_amdgcn_s_barrier();                                                       \
}

    // ---- prologue: stage tiles 0,1; PE for tiles 0,1 ----
    STAGE(0, 0)
    STAGE(1, 1)
    PELOAD(peE, 0)
    PELOAD(peO, 1)
    asm volatile("s_waitcnt vmcnt(0)" ::: "memory");
    __builtin_amdgcn_s_barrier();

    for (int tp = 0; tp < 16; ++tp) {
        const int e = 2 * tp;
        const int pfA = (e + 2 < 32) ? e + 2 : 31;
        const int pfB = (e + 3 < 32) ? e + 3 : 31;
        HALF(0, peE, e, pfA)          // tile e   from buf0; prefetch tile e+2
        HALF(1, peO, e + 1, pfB)      // tile e+1 from buf1; prefetch tile e+3
    }
#undef HALF
#undef COMPUTE32
#undef PELOAD
#undef STAGE

    // drain dangling DMA before LDS/block retirement
    asm volatile("s_waitcnt vmcnt(0)" ::: "memory");

    // ---- epilogue: combine l across lane-halves, normalize, store ----
    #pragma unroll
    for (int bi = 0; bi < 2; ++bi) {
        float lsum = lpart[bi] + __shfl_xor(lpart[bi], 32, 64);
        float inv = __builtin_amdgcn_rcpf(lsum);
        #pragma unroll
        for (int d0 = 0; d0 < 2; ++d0)
            #pragma unroll
            for (int r = 0; r < 16; r += 2) {
                float e0 = o[bi][d0][r] * inv;
                float e1 = o[bi][d0][r + 1] * inv;
                int d = d0 * 32 + ((r & 3) + 8 * (r >> 2)) + lh * 4;
                *(unsigned*)(Ob + ((size_t)bi * L_ + q0 + w * 32 + lq) * D_ + h * HD_ + d) = pk2(e0, e1);
            }
    }
}

// ---------------------------------------------------------------- launch
extern "C" void kernel_launch(void* const* d_in, const int* in_sizes, int n_in,
                              void* d_out, int out_size, void* d_ws, size_t ws_size,
                              hipStream_t stream) {
    const float* x  = (const float*)d_in[0];
    const float* pe = (const float*)d_in[1];
    const float* Wq = (const float*)d_in[2];
    const float* Wk = (const float*)d_in[3];
    const float* Wv = (const float*)d_in[4];
    const float* Wo = (const float*)d_in[5];
    float* out = (float*)d_out;

    const size_t MD = (size_t)4096 * 1024;
    const size_t HS = (size_t)BH_ * L_ * HD_;

    bf16* Xb  = (bf16*)d_ws;        // x in bf16            [4096][1024]
    bf16* WT  = Xb + MD;            // WqT|WkT|WvT|WoT      [4096][1024]
    bf16* Qb  = WT + MD;            // [bh][L][64]  (pre-scaled by 0.125*log2e)
    bf16* Kb  = Qb + HS;
    bf16* Vb  = Kb + HS;
    bf16* VTb = Vb + HS;            // [bh][64][L]
    bf16* Ob  = VTb + HS;           // attention out        [4096][1024]

    k_cast_x<<<2048, 256, 0, stream>>>(x, Xb, 4096 * 1024 / 8);
    k_cast_wT<<<dim3(16, 16, 4), 256, 0, stream>>>(Wq, Wk, Wv, Wo, WT);
    k_gemm<0><<<dim3(24, 32), 256, 0, stream>>>(Xb, WT, (void*)Qb);          // QKV, N=3072
    k_transpose_v<<<dim3(32, 32), 256, 0, stream>>>(Vb, VTb);
    k_attn<<<512, 128, 0, stream>>>(Qb, Kb, VTb, pe, Ob);
    k_gemm<1><<<dim3(8, 32), 256, 0, stream>>>(Ob, WT + (size_t)3072 * 1024, (void*)out); // out-proj
}

// Round 7
// 172.930 us; speedup vs baseline: 1.8353x; 1.1500x over previous
//
#include <hip/hip_runtime.h>
#include <hip/hip_bf16.h>
#include <stdint.h>

typedef __hip_bfloat16 bf16;
typedef __attribute__((ext_vector_type(8))) short bf16x8;   // 8 bf16 = 4 VGPRs (MFMA A/B frag)
typedef __attribute__((ext_vector_type(4))) float f32x4;    // 16x16 MFMA C/D frag
typedef __attribute__((ext_vector_type(16))) float f32x16;  // 32x32 MFMA C/D frag
typedef __attribute__((ext_vector_type(4))) unsigned u32x4;

#define B_  2
#define L_  2048
#define D_  1024
#define H_  16
#define HD_ 64
#define BH_ 32
#define L2E 1.4426950408889634f

#define DEV static __device__ __forceinline__

DEV short f2bf(float f) {
    bf16 h = __float2bfloat16(f);
    return __builtin_bit_cast(short, h);
}

DEV unsigned pk2(float lo, float hi) {   // bf16(lo) | bf16(hi)<<16
    unsigned a = (unsigned short)__builtin_bit_cast(unsigned short, __float2bfloat16(lo));
    unsigned b = (unsigned short)__builtin_bit_cast(unsigned short, __float2bfloat16(hi));
    return a | (b << 16);
}

DEV f32x4 mfma16(bf16x8 a, bf16x8 b, f32x4 c) {
    return __builtin_amdgcn_mfma_f32_16x16x32_bf16(a, b, c, 0, 0, 0);
}
DEV f32x16 mfma32(bf16x8 a, bf16x8 b, f32x16 c) {
    return __builtin_amdgcn_mfma_f32_32x32x16_bf16(a, b, c, 0, 0, 0);
}

// async global->LDS, 16B per lane; lds ptr must be wave-uniform (HW adds lane*16)
DEV void async_ld16(const void* g, void* lds_uniform) {
    __builtin_amdgcn_global_load_lds((const __attribute__((address_space(1))) void*)g,
                                     (__attribute__((address_space(3))) void*)lds_uniform,
                                     16, 0, 0);
}

// XOR-swizzled element offset inside a [rows][64] bf16 tile (128B rows).
DEV int swz(int row, int col) {
    int blk = (row << 3) + (col >> 3);
    blk ^= (row & 7);
    return (blk << 3) + (col & 7);
}

// ---------------------------------------------------------------- cast x -> bf16
__global__ __launch_bounds__(256) void k_cast_x(const float* __restrict__ x,
                                                bf16* __restrict__ xb, int n8) {
    int i = blockIdx.x * 256 + threadIdx.x;
    if (i >= n8) return;
    const float4* src = (const float4*)x + (size_t)i * 2;
    float4 a = src[0], b = src[1];
    bf16x8 v;
    v[0]=f2bf(a.x); v[1]=f2bf(a.y); v[2]=f2bf(a.z); v[3]=f2bf(a.w);
    v[4]=f2bf(b.x); v[5]=f2bf(b.y); v[6]=f2bf(b.z); v[7]=f2bf(b.w);
    *(bf16x8*)(xb + (size_t)i * 8) = v;
}

// ------------------------------------------- cast + transpose weights -> WT[n][k] bf16
__global__ __launch_bounds__(256) void k_cast_wT(const float* __restrict__ W0, const float* __restrict__ W1,
                                                 const float* __restrict__ W2, const float* __restrict__ W3,
                                                 bf16* __restrict__ WT) {
    const float* W = (blockIdx.z == 0) ? W0 : (blockIdx.z == 1) ? W1 : (blockIdx.z == 2) ? W2 : W3;
    __shared__ float tile[64][65];
    const int r0 = blockIdx.y * 64, c0 = blockIdx.x * 64;
    const int tx = threadIdx.x & 63, ty = threadIdx.x >> 6;
    #pragma unroll
    for (int i = 0; i < 16; ++i) {
        int r = ty + i * 4;
        tile[r][tx] = W[(size_t)(r0 + r) * D_ + c0 + tx];
    }
    __syncthreads();
    bf16* out = WT + (size_t)blockIdx.z * D_ * D_;
    #pragma unroll
    for (int i = 0; i < 16; ++i) {
        int n = ty + i * 4;
        out[(size_t)(c0 + n) * D_ + r0 + tx] = __float2bfloat16(tile[tx][n]);
    }
}

// ---------------------------------------------------------------- GEMM 128x128, BK=64
template <int MODE>
__global__ __launch_bounds__(256) void k_gemm(const bf16* __restrict__ A, const bf16* __restrict__ BT,
                                              void* __restrict__ C) {
    __shared__ __align__(16) bf16 As[128 * 64];
    __shared__ __align__(16) bf16 Bs[128 * 64];
    const int t = threadIdx.x;
    const int w = t >> 6, lane = t & 63;
    const int lr = lane & 15, lg = lane >> 4;
    const int wr = (w >> 1) * 64, wc = (w & 1) * 64;
    const size_t am0 = (size_t)blockIdx.y * 128;
    const size_t bn0 = (size_t)blockIdx.x * 128;

    f32x4 acc[4][4] = {};

    for (int kt = 0; kt < 1024 / 64; ++kt) {
        const int k0 = kt * 64;
        if (kt) __syncthreads();
        #pragma unroll
        for (int c = 0; c < 4; ++c) {
            int phys = c * 256 + t;
            int lb = phys ^ ((phys >> 3) & 7);
            int row = lb >> 3, cb = lb & 7;
            int ldsoff = (c * 256 + w * 64) * 8;
            async_ld16(A  + (am0 + row) * 1024 + k0 + cb * 8, (void*)(As + ldsoff));
            async_ld16(BT + (bn0 + row) * 1024 + k0 + cb * 8, (void*)(Bs + ldsoff));
        }
        __syncthreads();
        bf16x8 af[4][2], bfv[4][2];
        #pragma unroll
        for (int mi = 0; mi < 4; ++mi)
            #pragma unroll
            for (int ks = 0; ks < 2; ++ks)
                af[mi][ks] = *(const bf16x8*)(As + swz(wr + mi * 16 + lr, ks * 32 + lg * 8));
        #pragma unroll
        for (int ni = 0; ni < 4; ++ni)
            #pragma unroll
            for (int ks = 0; ks < 2; ++ks)
                bfv[ni][ks] = *(const bf16x8*)(Bs + swz(wc + ni * 16 + lr, ks * 32 + lg * 8));
        #pragma unroll
        for (int mi = 0; mi < 4; ++mi)
            #pragma unroll
            for (int ni = 0; ni < 4; ++ni) {
                acc[mi][ni] = mfma16(af[mi][0], bfv[ni][0], acc[mi][ni]);
                acc[mi][ni] = mfma16(af[mi][1], bfv[ni][1], acc[mi][ni]);
            }
    }

    #pragma unroll
    for (int mi = 0; mi < 4; ++mi)
        #pragma unroll
        for (int ni = 0; ni < 4; ++ni)
            #pragma unroll
            for (int j = 0; j < 4; ++j) {
                size_t gm = am0 + wr + mi * 16 + lg * 4 + j;
                size_t gn = bn0 + wc + ni * 16 + lr;
                float v = acc[mi][ni][j];
                if (MODE == 0) {
                    int which = (int)(gn >> 10);
                    int h = (int)((gn >> 6) & 15);
                    int d = (int)(gn & 63);
                    int bb = (int)(gm >> 11);
                    int l = (int)(gm & 2047);
                    // fold 0.125 * log2(e) into Q so attention works in exp2 domain
                    if (which == 0) v *= 0.18033688011112042f;
                    bf16* dst = (bf16*)C + (size_t)which * ((size_t)BH_ * L_ * HD_);
                    dst[((size_t)(bb * H_ + h) * L_ + l) * HD_ + d] = __float2bfloat16(v);
                } else {
                    ((float*)C)[gm * 1024 + gn] = v;
                }
            }
}

// ---------------------------------------------------------------- V transpose per head
__global__ __launch_bounds__(256) void k_transpose_v(const bf16* __restrict__ Vb, bf16* __restrict__ VTb) {
    __shared__ __align__(16) short tile[64][80];
    const int bh = blockIdx.y;
    const int l0 = blockIdx.x * 64;
    const int t = threadIdx.x;
    const int rr = t >> 2, cc = (t & 3) * 16;
    const short* src = (const short*)(Vb + ((size_t)bh * L_ + l0 + rr) * HD_ + cc);
    *(bf16x8*)&tile[rr][cc]     = *(const bf16x8*)src;
    *(bf16x8*)&tile[rr][cc + 8] = *(const bf16x8*)(src + 8);
    __syncthreads();
    bf16x8 v0, v1;
    #pragma unroll
    for (int i = 0; i < 8; ++i) v0[i] = tile[cc + i][rr];
    #pragma unroll
    for (int i = 0; i < 8; ++i) v1[i] = tile[cc + 8 + i][rr];
    short* dst = (short*)(VTb + ((size_t)bh * HD_ + rr) * L_ + l0 + cc);
    *(bf16x8*)dst       = v0;
    *(bf16x8*)(dst + 8) = v1;
}

// ---------------------------------------------------------------- fused attention
// grid 512 (XCD-swizzled: 2 heads/XCD), 256 threads = 4 waves = (qs 0..1) x (b 0..1).
// Wave: 32 q-rows (q0 = qt*64+qs*32), batch b, full 2048 kv in 64 tiles of 32.
// LDS per buf: K[2b] 8KB + V[2b] 8KB + PE[2qs] 8KB = 24KB; dbuf = 48KB -> 3 blocks/CU.
// K/V[b] shared by qs-waves; PE[qs] shared by b-waves. Each wave issues exactly 6
// DMAs/tile -> uniform counted vmcnt(6), depth-2 pipeline, never drained in-loop.
// Compute: R4/R6-verified pi-permuted 32x32 in-register softmax (zero cross-lane P).
__global__ __launch_bounds__(256, 3) void k_attn(const bf16* __restrict__ Qb, const bf16* __restrict__ Kb,
                                                 const bf16* __restrict__ VTb, const float* __restrict__ PE,
                                                 bf16* __restrict__ Ob) {
    __shared__ __align__(16) char shm[49152];

    const int bid = blockIdx.x;
    const int sw  = (bid & 7) * 64 + (bid >> 3);   // XCD swizzle (bijective, 512 = 8*64)
    const int qt  = sw & 31, h = sw >> 5;          // 2 heads per XCD -> K/V L2-resident
    const int t   = threadIdx.x;
    const int w   = t >> 6, l = t & 63;
    const int qs  = w & 1, b = w >> 1;
    const int q0  = qt * 64 + qs * 32;
    const int lq  = l & 31;         // this lane's q-row
    const int lh  = l >> 5;         // half selector within wave

    // pi(lq): involution swapping 4-blocks 1<->2 and 5<->6 (A-row m holds K[pi(m)])
    const int pb = (lq >> 2) & 3;
    const int prow = lq + (pb == 1 ? 4 : (pb == 2 ? -4 : 0));

    // Q B-fragments, hoisted (Q pre-scaled by 0.125*log2e at projection)
    bf16x8 Qf[4];
    #pragma unroll
    for (int dm = 0; dm < 4; ++dm)
        Qf[dm] = *(const bf16x8*)(Qb + ((size_t)(b * H_ + h) * L_ + q0 + lq) * HD_ + dm * 16 + lh * 8);

    const bf16*  kb  = Kb  + (size_t)(b * H_ + h) * L_ * HD_;
    const bf16*  vbp = VTb + (size_t)(b * H_ + h) * HD_ * L_;
    const float* peq = PE  + ((size_t)h * L_ + q0) * L_;

    // ---- staging source offsets (pre-swizzled so LDS stays linear; rule #21) ----
    const int k_srcoff  = (l >> 3) * HD_ + (((l & 7) ^ (l >> 3)) * 8);          // elements
    const int v_srcoff  = (l >> 2) * L_  + (((l & 3) ^ ((l >> 2) & 3)) * 8);    // elements
    const int pe_srcoff = (l >> 3) * L_  + (((l & 7) ^ (l >> 3)) * 4);          // floats

    // ---- LDS read offsets (swizzled) ----
    int kro[4];
    #pragma unroll
    for (int dm = 0; dm < 4; ++dm)
        kro[dm] = prow * 64 + (((dm * 2 + lh) ^ (prow & 7)) * 8);
    int vro[2][2];
    #pragma unroll
    for (int d0 = 0; d0 < 2; ++d0)
        #pragma unroll
        for (int m = 0; m < 2; ++m)
            vro[d0][m] = (d0 * 32 + lq) * 32 + (((m * 2 + lh) ^ (lq & 3)) * 8);
    int peo[4];
    #pragma unroll
    for (int g = 0; g < 4; ++g)
        peo[g] = lq * 32 + ((((g >> 1) * 4 + (g & 1) + lh * 2) ^ (lq & 7)) * 4);

    // LDS region bases (buf in {0,1})
#define SH_K(BUF)  (shm + (BUF) * 24576 + b * 4096)
#define SH_V(BUF)  (shm + (BUF) * 24576 + 8192 + b * 4096)
#define SH_PE(BUF) (shm + (BUF) * 24576 + 16384 + qs * 4096)

    f32x16 o[2] = {};
    float mrun = -3e38f, lpart = 0.f;

#define STAGE(BUF, TILE) {                                                              \
    const int kv0_ = (TILE) * 32;                                                       \
    _Pragma("unroll") for (int i = 0; i < 2; ++i) {                                     \
        const int c = 2 * qs + i;                                                       \
        async_ld16(kb + (size_t)(kv0_ + c * 8) * HD_ + k_srcoff, (void*)(SH_K(BUF) + c * 1024)); \
    }                                                                                   \
    _Pragma("unroll") for (int i = 0; i < 2; ++i) {                                     \
        const int c = 2 * qs + i;                                                       \
        async_ld16(vbp + (size_t)(c * 16) * L_ + kv0_ + v_srcoff, (void*)(SH_V(BUF) + c * 1024)); \
    }                                                                                   \
    _Pragma("unroll") for (int i = 0; i < 2; ++i) {                                     \
        const int c = 2 * b + i;                                                        \
        async_ld16(peq + (size_t)(c * 8) * L_ + kv0_ + pe_srcoff, (void*)(SH_PE(BUF) + c * 1024)); \
    }                                                                                   \
}

#define COMPUTE(BUF) {                                                                  \
    const bf16*  KL = (const bf16*)SH_K(BUF);                                           \
    const bf16*  VL = (const bf16*)SH_V(BUF);                                           \
    const float* PL = (const float*)SH_PE(BUF);                                         \
    bf16x8 kf0_ = *(const bf16x8*)(KL + kro[0]);                                        \
    bf16x8 kf1_ = *(const bf16x8*)(KL + kro[1]);                                        \
    bf16x8 kf2_ = *(const bf16x8*)(KL + kro[2]);                                        \
    bf16x8 kf3_ = *(const bf16x8*)(KL + kro[3]);                                        \
    f32x16 s = {};                                                                      \
    s = mfma32(kf0_, Qf[0], s);                                                         \
    s = mfma32(kf1_, Qf[1], s);                                                         \
    s = mfma32(kf2_, Qf[2], s);                                                         \
    s = mfma32(kf3_, Qf[3], s);                                                         \
    float4 pef_[4];                                                                     \
    _Pragma("unroll") for (int g = 0; g < 4; ++g)                                       \
        pef_[g] = *(const float4*)(PL + peo[g]);                                        \
    float v_[16];                                                                       \
    _Pragma("unroll") for (int r = 0; r < 16; ++r)                                      \
        v_[r] = fmaf(pef_[r >> 2][r & 3], L2E, s[r]);                                   \
    float t0_ = fmaxf(fmaxf(v_[0], v_[1]), fmaxf(v_[2], v_[3]));                        \
    float t1_ = fmaxf(fmaxf(v_[4], v_[5]), fmaxf(v_[6], v_[7]));                        \
    float t2_ = fmaxf(fmaxf(v_[8], v_[9]), fmaxf(v_[10], v_[11]));                      \
    float t3_ = fmaxf(fmaxf(v_[12], v_[13]), fmaxf(v_[14], v_[15]));                    \
    float vmh_ = fmaxf(fmaxf(t0_, t1_), fmaxf(t2_, t3_));                               \
    float vm_ = fmaxf(vmh_, __shfl_xor(vmh_, 32, 64));                                  \
    float mold_ = mrun;                                                                 \
    float mnew_ = mold_;                                                                \
    if (!__all(vm_ <= mold_ + 10.f)) {                                                  \
        mnew_ = fmaxf(mold_, vm_);                                                      \
        float scl_ = __builtin_amdgcn_exp2f(mold_ - mnew_);                             \
        mrun = mnew_;                                                                   \
        lpart *= scl_;                                                                  \
        _Pragma("unroll") for (int r = 0; r < 16; ++r) { o[0][r] *= scl_; o[1][r] *= scl_; } \
    }                                                                                   \
    float p_[16], ssum_ = 0.f;                                                          \
    _Pragma("unroll") for (int r = 0; r < 16; ++r) {                                    \
        p_[r] = __builtin_amdgcn_exp2f(v_[r] - mnew_);                                  \
        ssum_ += p_[r];                                                                 \
    }                                                                                   \
    lpart += ssum_;                                                                     \
    unsigned a_[8];                                                                     \
    _Pragma("unroll") for (int j = 0; j < 8; ++j)                                       \
        a_[j] = pk2(p_[2 * j], p_[2 * j + 1]);                                          \
    u32x4 w0v_ = { a_[0], a_[1], a_[2], a_[3] };                                        \
    u32x4 w1v_ = { a_[4], a_[5], a_[6], a_[7] };                                        \
    bf16x8 pf0_ = __builtin_bit_cast(bf16x8, w0v_);                                     \
    bf16x8 pf1_ = __builtin_bit_cast(bf16x8, w1v_);                                     \
    o[0] = mfma32(*(const bf16x8*)(VL + vro[0][0]), pf0_, o[0]);                        \
    o[0] = mfma32(*(const bf16x8*)(VL + vro[0][1]), pf1_, o[0]);                        \
    o[1] = mfma32(*(const bf16x8*)(VL + vro[1][0]), pf0_, o[1]);                        \
    o[1] = mfma32(*(const bf16x8*)(VL + vro[1][1]), pf1_, o[1]);                        \
}

    // ---- prologue: stage tiles 0 (buf0) and 1 (buf1) ----
    STAGE(0, 0)
    STAGE(1, 1)
    asm volatile("s_waitcnt vmcnt(6)" ::: "memory");   // tile 0 landed (own 6)
    __builtin_amdgcn_s_barrier();                      // everyone's tile 0 landed

    for (int tt = 0; tt < 64; ++tt) {
        const int buf = tt & 1;
        if (buf == 0) { COMPUTE(0) } else { COMPUTE(1) }
        __builtin_amdgcn_s_barrier();                  // all waves done reading buf
        const int pft = (tt + 2 < 64) ? tt + 2 : 63;
        if (buf == 0) { STAGE(0, pft) } else { STAGE(1, pft) }
        asm volatile("s_waitcnt vmcnt(6)" ::: "memory");   // tile tt+1 landed (own)
        __builtin_amdgcn_s_barrier();                      // everyone's tile tt+1 landed
    }
#undef COMPUTE
#undef STAGE
#undef SH_K
#undef SH_V
#undef SH_PE

    // drain dangling DMA before block retirement
    asm volatile("s_waitcnt vmcnt(0)" ::: "memory");

    // ---- epilogue: combine l across lane-halves, normalize, store ----
    float lsum = lpart + __shfl_xor(lpart, 32, 64);
    float inv = __builtin_amdgcn_rcpf(lsum);
    #pragma unroll
    for (int d0 = 0; d0 < 2; ++d0)
        #pragma unroll
        for (int r = 0; r < 16; r += 2) {
            float e0 = o[d0][r] * inv;
            float e1 = o[d0][r + 1] * inv;
            int d = d0 * 32 + ((r & 3) + 8 * (r >> 2)) + lh * 4;
            *(unsigned*)(Ob + ((size_t)b * L_ + q0 + lq) * D_ + h * HD_ + d) = pk2(e0, e1);
        }
}

// ---------------------------------------------------------------- launch
extern "C" void kernel_launch(void* const* d_in, const int* in_sizes, int n_in,
                              void* d_out, int out_size, void* d_ws, size_t ws_size,
                              hipStream_t stream) {
    const float* x  = (const float*)d_in[0];
    const float* pe = (const float*)d_in[1];
    const float* Wq = (const float*)d_in[2];
    const float* Wk = (const float*)d_in[3];
    const float* Wv = (const float*)d_in[4];
    const float* Wo = (const float*)d_in[5];
    float* out = (float*)d_out;

    const size_t MD = (size_t)4096 * 1024;
    const size_t HS = (size_t)BH_ * L_ * HD_;

    bf16* Xb  = (bf16*)d_ws;        // x in bf16            [4096][1024]
    bf16* WT  = Xb + MD;            // WqT|WkT|WvT|WoT      [4096][1024]
    bf16* Qb  = WT + MD;            // [bh][L][64]  (pre-scaled by 0.125*log2e)
    bf16* Kb  = Qb + HS;
    bf16* Vb  = Kb + HS;
    bf16* VTb = Vb + HS;            // [bh][64][L]
    bf16* Ob  = VTb + HS;           // attention out        [4096][1024]

    k_cast_x<<<2048, 256, 0, stream>>>(x, Xb, 4096 * 1024 / 8);
    k_cast_wT<<<dim3(16, 16, 4), 256, 0, stream>>>(Wq, Wk, Wv, Wo, WT);
    k_gemm<0><<<dim3(24, 32), 256, 0, stream>>>(Xb, WT, (void*)Qb);          // QKV, N=3072
    k_transpose_v<<<dim3(32, 32), 256, 0, stream>>>(Vb, VTb);
    k_attn<<<512, 256, 0, stream>>>(Qb, Kb, VTb, pe, Ob);
    k_gemm<1><<<dim3(8, 32), 256, 0, stream>>>(Ob, WT + (size_t)3072 * 1024, (void*)out); // out-proj
}